// Round 3
// baseline (319.619 us; speedup 1.0000x reference)
//
#include <hip/hip_runtime.h>
#include <hip/hip_bf16.h>

// Problem constants
#define BB   128   // batch
#define SS   37    // sensors
#define TT   2048  // time steps
#define DD   256   // d_model
#define STT  8     // static features
#define CC   2     // classes
#define MER  264   // DD + STT
#define FF   74    // 2*SS features

#define NC    4            // t-chunks per batch row
#define CHUNK (TT / NC)    // 512 = 2 x (64 lanes x float4)
#define NJ    (CHUNK / 256)// t-iterations per block (2)
#define RW    76           // partial row: 74 feature sums + cnt + tsum
#define NW    8            // waves per block (512 threads)
#define NSW   5            // sensors per wave (stride-8 interleave covers 37..40)

#define RED_BYTES (BB * NC * RW * 4)   // 155648 B of workspace for partials

// ---------------------------------------------------------------------------
// Fused kernel: 512 blocks x 512 threads.
// Phase 1 (all blocks): streaming reduction over T — identical arithmetic to
// the previous reduce_kernel (branch-free clamped sensor loads, shuffle
// reductions, one partial row red[blk][RW] per block).
// Completion: __threadfence + atomicAdd(cnt[b]) (device-scope release).
// Phase 2 (chunk-0 block of each batch only): spin until cnt[b]==4 (its 3
// sibling chunks done), __threadfence (device-scope acquire), then compute
// the whole per-batch head (pooled -> merge+relu -> classifier) with its 512
// threads. This overlaps the head with the reduce tail and removes one
// kernel dispatch + gap from the timed graph.
// Deadlock-free: spinners (128) wait only AFTER their own reduce; worst-case
// residency is 256 blocks (1/CU), so non-waiting blocks always have free
// slots to drain through. __launch_bounds__(512,4) caps VGPR<=128 so
// 2 blocks/CU (all 512) are in fact co-resident.
// ---------------------------------------------------------------------------
__global__ __launch_bounds__(512, 4) void fused_kernel(
    const float* __restrict__ x,      // [B,S,T]
    const int*   __restrict__ smk,    // [B,S,T]
    const float* __restrict__ tarr,   // [B,T]
    const float* __restrict__ statics,   // [B,ST]
    const float* __restrict__ W_sensor,  // [74,256]
    const float* __restrict__ b_sensor,  // [256]
    const float* __restrict__ W_time,    // [1,256]
    const float* __restrict__ b_time,    // [256]
    const float* __restrict__ W_static,  // [8,8]
    const float* __restrict__ b_static,  // [8]
    const float* __restrict__ W_merge,   // [264,264]
    const float* __restrict__ b_merge,   // [264]
    const float* __restrict__ W_cls,     // [264,2]
    const float* __restrict__ b_cls,     // [2]
    float* __restrict__ red,          // [B*NC, RW] partials (workspace)
    unsigned* __restrict__ cnt,       // [B] completion counters (memset 0)
    float* __restrict__ out)          // [B,2]
{
    const int blk   = blockIdx.x;      // 0 .. B*NC-1
    const int b     = blk >> 2;
    const int chunk = blk & 3;
    const int t0    = chunk * CHUNK;
    const int tid   = threadIdx.x;
    const int wave  = tid >> 6;
    const int lane  = tid & 63;

    // ---------------- Phase 1: reduction (identical to prior kernel) -------
    float ax[NSW];     // per-sensor x sums over this lane's t's
    float am[NSW];     // per-sensor mask sums
    unsigned nz = 0;   // nonzero flags: bit (4j+k) = t-slot k of iteration j
#pragma unroll
    for (int i = 0; i < NSW; ++i) { ax[i] = 0.f; am[i] = 0.f; }

#pragma unroll
    for (int j = 0; j < NJ; ++j) {
        const int tb = t0 + 256 * j + 4 * lane;
#pragma unroll
        for (int si = 0; si < NSW; ++si) {
            const int s_raw = wave + NW * si;               // 0..39, each once
            const int s     = (s_raw < SS) ? s_raw : (SS - 1);  // clamp, no branch
            const size_t base = ((size_t)(b * SS + s)) * TT + tb;
            const float4 xv = *(const float4*)(x + base);
            const int4   mv = *(const int4*)(smk + base);
            const float sx = (xv.x + xv.y) + (xv.z + xv.w);
            const float sm = (float)((mv.x + mv.y) + (mv.z + mv.w));
            ax[si] += (s_raw < SS) ? sx : 0.f;   // cndmask-predicated
            am[si] += (s_raw < SS) ? sm : 0.f;
            unsigned f = (unsigned)((xv.x != 0.f) | (mv.x != 0))
                       | ((unsigned)((xv.y != 0.f) | (mv.y != 0)) << 1)
                       | ((unsigned)((xv.z != 0.f) | (mv.z != 0)) << 2)
                       | ((unsigned)((xv.w != 0.f) | (mv.w != 0)) << 3);
            nz |= f << (4 * j);
        }
    }

    __shared__ unsigned nzp[NW][64];
    nzp[wave][lane] = nz;
    __syncthreads();

    float* __restrict__ rrow = red + (size_t)blk * RW;

    // wave 0: combine flags across waves, count + time-sum, shuffle-reduce
    if (wave == 0) {
        const unsigned m = (nzp[0][lane] | nzp[1][lane]) | (nzp[2][lane] | nzp[3][lane])
                         | (nzp[4][lane] | nzp[5][lane]) | (nzp[6][lane] | nzp[7][lane]);
        float cntv = 0.f, tsum = 0.f;
#pragma unroll
        for (int j = 0; j < NJ; ++j) {
            const float4 tv = *(const float4*)(tarr + (size_t)b * TT + t0 + 256 * j + 4 * lane);
            const unsigned mj = (m >> (4 * j)) & 0xFu;
            if (mj & 1u) { cntv += 1.f; tsum += tv.x; }
            if (mj & 2u) { cntv += 1.f; tsum += tv.y; }
            if (mj & 4u) { cntv += 1.f; tsum += tv.z; }
            if (mj & 8u) { cntv += 1.f; tsum += tv.w; }
        }
        for (int off = 32; off; off >>= 1) {
            cntv += __shfl_down(cntv, off, 64);
            tsum += __shfl_down(tsum, off, 64);
        }
        if (lane == 0) { rrow[74] = cntv; rrow[75] = tsum; }
    }

    // per-sensor sums: wave shuffle reduction, one plain store per value
#pragma unroll
    for (int si = 0; si < NSW; ++si) {
        const int s_raw = wave + NW * si;
        float vx = ax[si], vm = am[si];
        for (int off = 32; off; off >>= 1) {
            vx += __shfl_down(vx, off, 64);
            vm += __shfl_down(vm, off, 64);
        }
        if (lane == 0 && s_raw < SS) { rrow[s_raw] = vx; rrow[SS + s_raw] = vm; }
    }

    // ---------------- release: partials visible device-wide ----------------
    __threadfence();          // each thread flushes its own stores (device scope)
    __syncthreads();          // intra-block HB: all stores ordered before tid0's atomic
    if (tid == 0) atomicAdd(&cnt[b], 1u);

    if (chunk != 0) return;   // only the chunk-0 block runs the head for batch b

    // ---------------- Phase 2: per-batch head (overlapped) -----------------
    if (tid == 0) {
        while (__hip_atomic_load(&cnt[b], __ATOMIC_RELAXED, __HIP_MEMORY_SCOPE_AGENT) < 4u)
            __builtin_amdgcn_s_sleep(2);
        __threadfence();      // device-scope acquire: order spin before red[] loads
    }
    __syncthreads();
    __threadfence();          // all waves: invalidate L1 before reading red[]

    __shared__ float sred[RW];
    __shared__ float comb[MER];
    __shared__ float comb2[MER];
    __shared__ float rbuf[16];

    if (tid < RW) {
        const float* rb = red + (size_t)b * NC * RW + tid;
        sred[tid] = (rb[0] + rb[RW]) + (rb[2 * RW] + rb[3 * RW]);
    }
    __syncthreads();

    const float smask = sred[74];
    const float stime = sred[75];
    const float inv   = 1.0f / fmaxf(smask, 1e-9f);

    if (tid < DD) {
        // pooled: one output dim per thread, fully unrolled (74 loads in flight)
        const int d = tid;
        float a0 = smask * (b_sensor[d] + b_time[d]) + stime * W_time[d];
        float a1 = 0.f;
#pragma unroll
        for (int f = 0; f < FF; f += 2) {
            a0 += sred[f]     * W_sensor[f * DD + d];
            a1 += sred[f + 1] * W_sensor[(f + 1) * DD + d];
        }
        comb[d] = (a0 + a1) * inv;
    } else if (tid < DD + STT) {
        const int j = tid - DD;
        float acc = b_static[j];
#pragma unroll
        for (int i = 0; i < STT; ++i)
            acc += statics[b * STT + i] * W_static[i * STT + j];
        comb[DD + j] = acc;
    }
    __syncthreads();

    // merge layer: one output per thread, 8-way unrolled inner loop
    if (tid < MER) {
        const int j = tid;
        float a[8];
#pragma unroll
        for (int k = 0; k < 8; ++k) a[k] = 0.f;
        for (int i = 0; i < MER; i += 8) {   // 264 = 33 * 8
#pragma unroll
            for (int k = 0; k < 8; ++k)
                a[k] += comb[i + k] * W_merge[(i + k) * MER + j];
        }
        const float acc = b_merge[j] +
            ((a[0] + a[1]) + (a[2] + a[3])) + ((a[4] + a[5]) + (a[6] + a[7]));
        comb2[j] = fmaxf(acc, 0.f);
    }
    __syncthreads();

    // classifier: parallel over i, block reduction (waves 5..7 contribute +0.f)
    float c0 = 0.f, c1 = 0.f;
    if (tid < MER) {
        const float v = comb2[tid];
        c0 = v * W_cls[tid * CC];
        c1 = v * W_cls[tid * CC + 1];
    }
    for (int off = 32; off; off >>= 1) {
        c0 += __shfl_down(c0, off, 64);
        c1 += __shfl_down(c1, off, 64);
    }
    if (lane == 0) { rbuf[wave] = c0; rbuf[8 + wave] = c1; }
    __syncthreads();
    if (tid == 0)
        out[b * CC + 0] = b_cls[0] + rbuf[0] + rbuf[1] + rbuf[2] + rbuf[3]
                        + rbuf[4] + rbuf[5] + rbuf[6] + rbuf[7];
    if (tid == 1)
        out[b * CC + 1] = b_cls[1] + rbuf[8] + rbuf[9] + rbuf[10] + rbuf[11]
                        + rbuf[12] + rbuf[13] + rbuf[14] + rbuf[15];
}

extern "C" void kernel_launch(void* const* d_in, const int* in_sizes, int n_in,
                              void* d_out, int out_size, void* d_ws, size_t ws_size,
                              hipStream_t stream) {
    const float* x        = (const float*)d_in[0];
    const float* statics  = (const float*)d_in[1];
    const float* tarr     = (const float*)d_in[2];
    const int*   smk      = (const int*)  d_in[3];
    const float* W_sensor = (const float*)d_in[4];
    const float* b_sensor = (const float*)d_in[5];
    const float* W_time   = (const float*)d_in[6];
    const float* b_time   = (const float*)d_in[7];
    const float* W_static = (const float*)d_in[8];
    const float* b_static = (const float*)d_in[9];
    const float* W_merge  = (const float*)d_in[10];
    const float* b_merge  = (const float*)d_in[11];
    const float* W_cls    = (const float*)d_in[12];
    const float* b_cls    = (const float*)d_in[13];
    float* out = (float*)d_out;
    float* red = (float*)d_ws;                       // [B*NC, RW] partials
    unsigned* cnt = (unsigned*)((char*)d_ws + RED_BYTES);  // [B] counters

    // zero the 128 per-batch completion counters (512 B; capture-legal)
    (void)hipMemsetAsync(cnt, 0, BB * sizeof(unsigned), stream);

    fused_kernel<<<BB * NC, 512, 0, stream>>>(x, smk, tarr, statics,
                                              W_sensor, b_sensor, W_time, b_time,
                                              W_static, b_static, W_merge, b_merge,
                                              W_cls, b_cls, red, cnt, out);
}

// Round 4
// 141.175 us; speedup vs baseline: 2.2640x; 2.2640x over previous
//
#include <hip/hip_runtime.h>
#include <hip/hip_bf16.h>

// Problem constants
#define BB   128   // batch
#define SS   37    // sensors
#define TT   2048  // time steps
#define DD   256   // d_model
#define STT  8     // static features
#define CC   2     // classes
#define MER  264   // DD + STT
#define FF   74    // 2*SS features

#define NC    8            // t-chunks per batch row (8 -> 1024 blocks, 100% occ)
#define CHUNK (TT / NC)    // 256 = 64 lanes x float4
#define NJ    (CHUNK / 256)// t-iterations per block (1)
#define RW    76           // partial row: 74 feature sums + cnt + tsum
#define NW    8            // waves per block (512 threads)
#define NSW   5            // sensors per wave (stride-8 interleave covers 37..40)

// ---------------------------------------------------------------------------
// Kernel 1: streaming reduction over T. 1024 blocks x 512 threads.
// 56 VGPR / 2 KB LDS -> 4 blocks/CU x 8 waves = 32 waves/CU (100% occupancy;
// was 50% at NC=4). Branch-free inner loop: every wave does exactly NSW
// sensor-load-pairs (out-of-range s clamped to 36 and its contribution zeroed
// via cndmask), so all loads issue as one unbroken burst — no s_cbranch
// between loads, fine-grained vmcnt overlap.
// Block (b, chunk) writes its own partial row red[b*NC+chunk][RW]; no
// atomics, no fences, no zero-init.
//   row[s]    = sum_t x[b,s,t]       (mask*x == x since mask==0 => all 0)
//   row[37+s] = sum_t smk[b,s,t]
//   row[74]   = sum_t mask[b,t],  row[75] = sum_t mask[b,t]*time[b,t]
// ---------------------------------------------------------------------------
__global__ __launch_bounds__(512, 8) void reduce_kernel(
    const float* __restrict__ x,      // [B,S,T]
    const int*   __restrict__ smk,    // [B,S,T]
    const float* __restrict__ tarr,   // [B,T]
    float* __restrict__ red)          // [B*NC, RW] partials
{
    const int blk   = blockIdx.x;      // 0 .. B*NC-1
    const int b     = blk >> 3;
    const int chunk = blk & 7;
    const int t0    = chunk * CHUNK;
    const int wave  = threadIdx.x >> 6;
    const int lane  = threadIdx.x & 63;

    float ax[NSW];     // per-sensor x sums over this lane's t's
    float am[NSW];     // per-sensor mask sums
    unsigned nz = 0;   // nonzero flags: bit k = t-slot k of this lane
#pragma unroll
    for (int i = 0; i < NSW; ++i) { ax[i] = 0.f; am[i] = 0.f; }

    {
        const int tb = t0 + 4 * lane;
#pragma unroll
        for (int si = 0; si < NSW; ++si) {
            const int s_raw = wave + NW * si;               // 0..39, each once
            const int s     = (s_raw < SS) ? s_raw : (SS - 1);  // clamp, no branch
            const size_t base = ((size_t)(b * SS + s)) * TT + tb;
            const float4 xv = *(const float4*)(x + base);
            const int4   mv = *(const int4*)(smk + base);
            const float sx = (xv.x + xv.y) + (xv.z + xv.w);
            const float sm = (float)((mv.x + mv.y) + (mv.z + mv.w));
            ax[si] += (s_raw < SS) ? sx : 0.f;   // cndmask-predicated
            am[si] += (s_raw < SS) ? sm : 0.f;
            // nz from clamped s=36 re-reads is idempotent (same flags, OR)
            unsigned f = (unsigned)((xv.x != 0.f) | (mv.x != 0))
                       | ((unsigned)((xv.y != 0.f) | (mv.y != 0)) << 1)
                       | ((unsigned)((xv.z != 0.f) | (mv.z != 0)) << 2)
                       | ((unsigned)((xv.w != 0.f) | (mv.w != 0)) << 3);
            nz |= f;
        }
    }

    __shared__ unsigned nzp[NW][64];
    nzp[wave][lane] = nz;
    __syncthreads();

    float* __restrict__ rrow = red + (size_t)blk * RW;

    // wave 0: combine flags across waves, count + time-sum, shuffle-reduce
    if (wave == 0) {
        const unsigned m = (nzp[0][lane] | nzp[1][lane]) | (nzp[2][lane] | nzp[3][lane])
                         | (nzp[4][lane] | nzp[5][lane]) | (nzp[6][lane] | nzp[7][lane]);
        float cnt = 0.f, tsum = 0.f;
        {
            const float4 tv = *(const float4*)(tarr + (size_t)b * TT + t0 + 4 * lane);
            if (m & 1u) { cnt += 1.f; tsum += tv.x; }
            if (m & 2u) { cnt += 1.f; tsum += tv.y; }
            if (m & 4u) { cnt += 1.f; tsum += tv.z; }
            if (m & 8u) { cnt += 1.f; tsum += tv.w; }
        }
        for (int off = 32; off; off >>= 1) {
            cnt  += __shfl_down(cnt,  off, 64);
            tsum += __shfl_down(tsum, off, 64);
        }
        if (lane == 0) { rrow[74] = cnt; rrow[75] = tsum; }
    }

    // per-sensor sums: wave shuffle reduction, one plain store per value
#pragma unroll
    for (int si = 0; si < NSW; ++si) {
        const int s_raw = wave + NW * si;
        float vx = ax[si], vm = am[si];
        for (int off = 32; off; off >>= 1) {
            vx += __shfl_down(vx, off, 64);
            vm += __shfl_down(vm, off, 64);
        }
        if (lane == 0 && s_raw < SS) { rrow[s_raw] = vx; rrow[SS + s_raw] = vm; }
    }
}

// ---------------------------------------------------------------------------
// Kernel 2: per-batch head, 320 threads per block, one block per b.
// Sums the NC chunk-partials, then:
// pooled = (sxt @ W_sensor + smask*(b_sensor+b_time) + stime*W_time) / denom
// comb   = relu([pooled, static@W_static+b_static] @ W_merge + b_merge)
// out    = comb @ W_cls + b_cls
// ---------------------------------------------------------------------------
__global__ __launch_bounds__(320) void head_kernel(
    const float* __restrict__ red,       // [B*NC, RW]
    const float* __restrict__ statics,   // [B,ST]
    const float* __restrict__ W_sensor,  // [74,256]
    const float* __restrict__ b_sensor,  // [256]
    const float* __restrict__ W_time,    // [1,256]
    const float* __restrict__ b_time,    // [256]
    const float* __restrict__ W_static,  // [8,8]
    const float* __restrict__ b_static,  // [8]
    const float* __restrict__ W_merge,   // [264,264]
    const float* __restrict__ b_merge,   // [264]
    const float* __restrict__ W_cls,     // [264,2]
    const float* __restrict__ b_cls,     // [2]
    float* __restrict__ out)             // [B,2]
{
    const int b   = blockIdx.x;
    const int tid = threadIdx.x;

    __shared__ float sred[RW];
    __shared__ float comb[MER];
    __shared__ float comb2[MER];
    __shared__ float rbuf[10];

    if (tid < RW) {
        const float* rb = red + (size_t)b * NC * RW + tid;
        const float s01 = rb[0]      + rb[RW];
        const float s23 = rb[2 * RW] + rb[3 * RW];
        const float s45 = rb[4 * RW] + rb[5 * RW];
        const float s67 = rb[6 * RW] + rb[7 * RW];
        sred[tid] = (s01 + s23) + (s45 + s67);
    }
    __syncthreads();

    const float smask = sred[74];
    const float stime = sred[75];
    const float inv   = 1.0f / fmaxf(smask, 1e-9f);

    if (tid < DD) {
        // pooled: one output dim per thread, fully unrolled (74 loads in flight)
        const int d = tid;
        float a0 = smask * (b_sensor[d] + b_time[d]) + stime * W_time[d];
        float a1 = 0.f;
#pragma unroll
        for (int f = 0; f < FF; f += 2) {
            a0 += sred[f]     * W_sensor[f * DD + d];
            a1 += sred[f + 1] * W_sensor[(f + 1) * DD + d];
        }
        comb[d] = (a0 + a1) * inv;
    } else if (tid < DD + STT) {
        const int j = tid - DD;
        float acc = b_static[j];
#pragma unroll
        for (int i = 0; i < STT; ++i)
            acc += statics[b * STT + i] * W_static[i * STT + j];
        comb[DD + j] = acc;
    }
    __syncthreads();

    // merge layer: one output per thread, 8-way unrolled inner loop
    if (tid < MER) {
        const int j = tid;
        float a[8];
#pragma unroll
        for (int k = 0; k < 8; ++k) a[k] = 0.f;
        for (int i = 0; i < MER; i += 8) {   // 264 = 33 * 8
#pragma unroll
            for (int k = 0; k < 8; ++k)
                a[k] += comb[i + k] * W_merge[(i + k) * MER + j];
        }
        const float acc = b_merge[j] +
            ((a[0] + a[1]) + (a[2] + a[3])) + ((a[4] + a[5]) + (a[6] + a[7]));
        comb2[j] = fmaxf(acc, 0.f);
    }
    __syncthreads();

    // classifier: parallel over i, block reduction
    float c0 = 0.f, c1 = 0.f;
    if (tid < MER) {
        const float v = comb2[tid];
        c0 = v * W_cls[tid * CC];
        c1 = v * W_cls[tid * CC + 1];
    }
    for (int off = 32; off; off >>= 1) {
        c0 += __shfl_down(c0, off, 64);
        c1 += __shfl_down(c1, off, 64);
    }
    const int wv = tid >> 6, ln = tid & 63;
    if (ln == 0) { rbuf[wv] = c0; rbuf[5 + wv] = c1; }
    __syncthreads();
    if (tid == 0)
        out[b * CC + 0] = b_cls[0] + rbuf[0] + rbuf[1] + rbuf[2] + rbuf[3] + rbuf[4];
    if (tid == 1)
        out[b * CC + 1] = b_cls[1] + rbuf[5] + rbuf[6] + rbuf[7] + rbuf[8] + rbuf[9];
}

extern "C" void kernel_launch(void* const* d_in, const int* in_sizes, int n_in,
                              void* d_out, int out_size, void* d_ws, size_t ws_size,
                              hipStream_t stream) {
    const float* x        = (const float*)d_in[0];
    const float* statics  = (const float*)d_in[1];
    const float* tarr     = (const float*)d_in[2];
    const int*   smk      = (const int*)  d_in[3];
    const float* W_sensor = (const float*)d_in[4];
    const float* b_sensor = (const float*)d_in[5];
    const float* W_time   = (const float*)d_in[6];
    const float* b_time   = (const float*)d_in[7];
    const float* W_static = (const float*)d_in[8];
    const float* b_static = (const float*)d_in[9];
    const float* W_merge  = (const float*)d_in[10];
    const float* b_merge  = (const float*)d_in[11];
    const float* W_cls    = (const float*)d_in[12];
    const float* b_cls    = (const float*)d_in[13];
    float* out = (float*)d_out;
    float* red = (float*)d_ws;   // [B*NC, RW] floats — every slot overwritten
                                 // each call, so no zero-init needed

    reduce_kernel<<<BB * NC, 512, 0, stream>>>(x, smk, tarr, red);
    head_kernel<<<BB, 320, 0, stream>>>(red, statics, W_sensor, b_sensor,
                                        W_time, b_time, W_static, b_static,
                                        W_merge, b_merge, W_cls, b_cls, out);
}

// Round 5
// 136.770 us; speedup vs baseline: 2.3369x; 1.0322x over previous
//
#include <hip/hip_runtime.h>
#include <hip/hip_bf16.h>

// Problem constants
#define BB   128   // batch
#define SS   37    // sensors
#define TT   2048  // time steps
#define DD   256   // d_model
#define STT  8     // static features
#define CC   2     // classes
#define MER  264   // DD + STT
#define FF   74    // 2*SS features

#define NC    4            // t-chunks per batch row (best-known config, R1)
#define CHUNK (TT / NC)    // 512 = 2 x (64 lanes x float4)
#define NJ    (CHUNK / 256)// t-iterations per block (2)
#define RW    76           // partial row: 74 feature sums + cnt + tsum
#define NW    8            // waves per block (512 threads)
#define NSW   5            // sensors per wave (stride-8 interleave covers 37..40)

// ---------------------------------------------------------------------------
// Kernel 1: streaming reduction over T. 512 blocks x 512 threads.
// VALU-minimized inner loop (R5): the t-validity flags are built with bitwise
// OR-accumulators — o |= (x_bits<<1) | m_bits — 2 VALU/component instead of
// cmp+cndmask+or chains; the !=0 compare happens ONCE, in wave 0, after the
// per-wave OR-words are combined through LDS. Accumulation predication for
// the clamped s>=37 rows is removed entirely: their ax/am garbage is never
// stored (epilogue guards s_raw<SS). Mask sums accumulate as int, one cvt in
// the epilogue. Loads/bytes/addresses identical to the R1 kernel.
//   row[s]    = sum_t x[b,s,t]       (mask*x == x since mask==0 => all 0)
//   row[37+s] = sum_t smk[b,s,t]
//   row[74]   = sum_t mask[b,t],  row[75] = sum_t mask[b,t]*time[b,t]
// ---------------------------------------------------------------------------
__global__ __launch_bounds__(512) void reduce_kernel(
    const float* __restrict__ x,      // [B,S,T]
    const int*   __restrict__ smk,    // [B,S,T]
    const float* __restrict__ tarr,   // [B,T]
    float* __restrict__ red)          // [B*NC, RW] partials
{
    const int blk   = blockIdx.x;      // 0 .. B*NC-1
    const int b     = blk >> 2;
    const int chunk = blk & 3;
    const int t0    = chunk * CHUNK;
    const int wave  = threadIdx.x >> 6;
    const int lane  = threadIdx.x & 63;

    float ax[NSW];     // per-sensor x sums over this lane's t's
    int   am[NSW];     // per-sensor mask sums (int; cvt once at end)
#pragma unroll
    for (int i = 0; i < NSW; ++i) { ax[i] = 0.f; am[i] = 0; }

    // per-j OR-words: nonzero iff any sensor had a nonzero at that t-slot
    __shared__ uint4 nzp[NJ][NW][64];

#pragma unroll
    for (int j = 0; j < NJ; ++j) {
        const int tb = t0 + 256 * j + 4 * lane;
        unsigned o0 = 0u, o1 = 0u, o2 = 0u, o3 = 0u;
#pragma unroll
        for (int si = 0; si < NSW; ++si) {
            const int s_raw = wave + NW * si;               // 0..39, each once
            const int s     = (s_raw < SS) ? s_raw : (SS - 1);  // clamp (SALU)
            const size_t base = ((size_t)(b * SS + s)) * TT + tb;
            const float4 xv = *(const float4*)(x + base);
            const int4   mv = *(const int4*)(smk + base);
            ax[si] += (xv.x + xv.y) + (xv.z + xv.w);   // clamped-row garbage
            am[si] += (mv.x + mv.y) + (mv.z + mv.w);   //   is never stored
            // x != 0  <=>  (bits<<1) != 0  (strips sign; ±0 -> 0, NaN/Inf -> nz)
            // m != 0  <=>  bits != 0
            o0 |= (__float_as_uint(xv.x) << 1) | (unsigned)mv.x;
            o1 |= (__float_as_uint(xv.y) << 1) | (unsigned)mv.y;
            o2 |= (__float_as_uint(xv.z) << 1) | (unsigned)mv.z;
            o3 |= (__float_as_uint(xv.w) << 1) | (unsigned)mv.w;
        }
        nzp[j][wave][lane] = make_uint4(o0, o1, o2, o3);
    }
    __syncthreads();

    float* __restrict__ rrow = red + (size_t)blk * RW;

    // wave 0: OR flags across waves, count + time-sum, shuffle-reduce
    if (wave == 0) {
        float cnt = 0.f, tsum = 0.f;
#pragma unroll
        for (int j = 0; j < NJ; ++j) {
            uint4 m = nzp[j][0][lane];
#pragma unroll
            for (int w = 1; w < NW; ++w) {
                const uint4 v = nzp[j][w][lane];
                m.x |= v.x; m.y |= v.y; m.z |= v.z; m.w |= v.w;
            }
            const float4 tv = *(const float4*)(tarr + (size_t)b * TT + t0 + 256 * j + 4 * lane);
            if (m.x) { cnt += 1.f; tsum += tv.x; }
            if (m.y) { cnt += 1.f; tsum += tv.y; }
            if (m.z) { cnt += 1.f; tsum += tv.z; }
            if (m.w) { cnt += 1.f; tsum += tv.w; }
        }
        for (int off = 32; off; off >>= 1) {
            cnt  += __shfl_down(cnt,  off, 64);
            tsum += __shfl_down(tsum, off, 64);
        }
        if (lane == 0) { rrow[74] = cnt; rrow[75] = tsum; }
    }

    // per-sensor sums: wave shuffle reduction, one plain store per value
#pragma unroll
    for (int si = 0; si < NSW; ++si) {
        const int s_raw = wave + NW * si;
        float vx = ax[si], vm = (float)am[si];
        for (int off = 32; off; off >>= 1) {
            vx += __shfl_down(vx, off, 64);
            vm += __shfl_down(vm, off, 64);
        }
        if (lane == 0 && s_raw < SS) { rrow[s_raw] = vx; rrow[SS + s_raw] = vm; }
    }
}

// ---------------------------------------------------------------------------
// Kernel 2: per-batch head, 320 threads per block, one block per b.
// Sums the NC chunk-partials, then:
// pooled = (sxt @ W_sensor + smask*(b_sensor+b_time) + stime*W_time) / denom
// comb   = relu([pooled, static@W_static+b_static] @ W_merge + b_merge)
// out    = comb @ W_cls + b_cls
// ---------------------------------------------------------------------------
__global__ __launch_bounds__(320) void head_kernel(
    const float* __restrict__ red,       // [B*NC, RW]
    const float* __restrict__ statics,   // [B,ST]
    const float* __restrict__ W_sensor,  // [74,256]
    const float* __restrict__ b_sensor,  // [256]
    const float* __restrict__ W_time,    // [1,256]
    const float* __restrict__ b_time,    // [256]
    const float* __restrict__ W_static,  // [8,8]
    const float* __restrict__ b_static,  // [8]
    const float* __restrict__ W_merge,   // [264,264]
    const float* __restrict__ b_merge,   // [264]
    const float* __restrict__ W_cls,     // [264,2]
    const float* __restrict__ b_cls,     // [2]
    float* __restrict__ out)             // [B,2]
{
    const int b   = blockIdx.x;
    const int tid = threadIdx.x;

    __shared__ float sred[RW];
    __shared__ float comb[MER];
    __shared__ float comb2[MER];
    __shared__ float rbuf[10];

    if (tid < RW) {
        const float* rb = red + (size_t)b * NC * RW + tid;
        sred[tid] = (rb[0] + rb[RW]) + (rb[2 * RW] + rb[3 * RW]);
    }
    __syncthreads();

    const float smask = sred[74];
    const float stime = sred[75];
    const float inv   = 1.0f / fmaxf(smask, 1e-9f);

    if (tid < DD) {
        // pooled: one output dim per thread, fully unrolled (74 loads in flight)
        const int d = tid;
        float a0 = smask * (b_sensor[d] + b_time[d]) + stime * W_time[d];
        float a1 = 0.f;
#pragma unroll
        for (int f = 0; f < FF; f += 2) {
            a0 += sred[f]     * W_sensor[f * DD + d];
            a1 += sred[f + 1] * W_sensor[(f + 1) * DD + d];
        }
        comb[d] = (a0 + a1) * inv;
    } else if (tid < DD + STT) {
        const int j = tid - DD;
        float acc = b_static[j];
#pragma unroll
        for (int i = 0; i < STT; ++i)
            acc += statics[b * STT + i] * W_static[i * STT + j];
        comb[DD + j] = acc;
    }
    __syncthreads();

    // merge layer: one output per thread, 8-way unrolled inner loop
    if (tid < MER) {
        const int j = tid;
        float a[8];
#pragma unroll
        for (int k = 0; k < 8; ++k) a[k] = 0.f;
        for (int i = 0; i < MER; i += 8) {   // 264 = 33 * 8
#pragma unroll
            for (int k = 0; k < 8; ++k)
                a[k] += comb[i + k] * W_merge[(i + k) * MER + j];
        }
        const float acc = b_merge[j] +
            ((a[0] + a[1]) + (a[2] + a[3])) + ((a[4] + a[5]) + (a[6] + a[7]));
        comb2[j] = fmaxf(acc, 0.f);
    }
    __syncthreads();

    // classifier: parallel over i, block reduction
    float c0 = 0.f, c1 = 0.f;
    if (tid < MER) {
        const float v = comb2[tid];
        c0 = v * W_cls[tid * CC];
        c1 = v * W_cls[tid * CC + 1];
    }
    for (int off = 32; off; off >>= 1) {
        c0 += __shfl_down(c0, off, 64);
        c1 += __shfl_down(c1, off, 64);
    }
    const int wv = tid >> 6, ln = tid & 63;
    if (ln == 0) { rbuf[wv] = c0; rbuf[5 + wv] = c1; }
    __syncthreads();
    if (tid == 0)
        out[b * CC + 0] = b_cls[0] + rbuf[0] + rbuf[1] + rbuf[2] + rbuf[3] + rbuf[4];
    if (tid == 1)
        out[b * CC + 1] = b_cls[1] + rbuf[5] + rbuf[6] + rbuf[7] + rbuf[8] + rbuf[9];
}

extern "C" void kernel_launch(void* const* d_in, const int* in_sizes, int n_in,
                              void* d_out, int out_size, void* d_ws, size_t ws_size,
                              hipStream_t stream) {
    const float* x        = (const float*)d_in[0];
    const float* statics  = (const float*)d_in[1];
    const float* tarr     = (const float*)d_in[2];
    const int*   smk      = (const int*)  d_in[3];
    const float* W_sensor = (const float*)d_in[4];
    const float* b_sensor = (const float*)d_in[5];
    const float* W_time   = (const float*)d_in[6];
    const float* b_time   = (const float*)d_in[7];
    const float* W_static = (const float*)d_in[8];
    const float* b_static = (const float*)d_in[9];
    const float* W_merge  = (const float*)d_in[10];
    const float* b_merge  = (const float*)d_in[11];
    const float* W_cls    = (const float*)d_in[12];
    const float* b_cls    = (const float*)d_in[13];
    float* out = (float*)d_out;
    float* red = (float*)d_ws;   // [B*NC, RW] floats — every slot overwritten
                                 // each call, so no zero-init needed

    reduce_kernel<<<BB * NC, 512, 0, stream>>>(x, smk, tarr, red);
    head_kernel<<<BB, 320, 0, stream>>>(red, statics, W_sensor, b_sensor,
                                        W_time, b_time, W_static, b_static,
                                        W_merge, b_merge, W_cls, b_cls, out);
}